// Round 11
// baseline (117.929 us; speedup 1.0000x reference)
//
#include <hip/hip_runtime.h>

// ROIPatchExtractor: B=32, C=3, H=W=448, 2x2 patches -> N=128 samples.
// Composed separable bilinear: each output row/col = weighted 3-tap sum of
// <=3 consecutive patch rows/cols.
//
// r11 = r10 all-register data path + ENTRY PRECOMPUTE KERNEL.
// Post-mortem r2-r10: all structures land 105-115us; the common cost is the
// per-thread make_entry prologue (~45 VALU ops x 448 lanes ~= 7us/CU per
// call-per-thread; r10 ran ~2, recomputed identically by all 56 blocks of a
// sample). Kernel 1 computes colE[n][col] / rowE[n][row] float4 tables into
// d_ws (1.83 MB, L2-resident); kernel 2's prologue is 2 dwordx4 loads + one
// uniform dword instead. Data path identical -> absmax unchanged.

#define IMG 448
#define PATCH 224
#define ROWS 8     // output rows per block; grid.x = 448/8 = 56
#define NPR 8      // padded patch-row window (k0<=4, +3 taps -> 7; pad to 8)
#define NTAB (128 * IMG)   // entries per table

#define SOFT_BARRIER()                                          \
    do {                                                        \
        asm volatile("s_waitcnt lgkmcnt(0)" ::: "memory");      \
        __builtin_amdgcn_s_barrier();                           \
        asm volatile("" ::: "memory");                          \
    } while (0)

__device__ inline float4 make_entry(int t, int crop, int off) {
    // stage 2: output coord t -> up-image coords u0,u1 with weight wy
    float cf = (float)crop;
    float s = ((float)t + 0.5f) * cf / 448.0f - 0.5f;
    s = fminf(fmaxf(s, 0.0f), cf - 1.0f);
    int i0 = (int)s;                 // s >= 0, trunc == floor
    int i1 = min(i0 + 1, crop - 1);
    float wy = s - (float)i0;
    int u0 = off + i0;
    int u1 = off + i1;
    // stage 1: up coord u -> patch coord: s1 = 0.5*u - 0.25, clamp [0,223]
    float t0 = fminf(fmaxf(0.5f * (float)u0 - 0.25f, 0.0f), 223.0f);
    int a0 = (int)t0;
    int a1 = min(a0 + 1, 223);
    float f0 = t0 - (float)a0;
    float t1 = fminf(fmaxf(0.5f * (float)u1 - 0.25f, 0.0f), 223.0f);
    int b0 = (int)t1;
    int b1 = min(b0 + 1, 223);
    float f1 = t1 - (float)b0;
    // fold 4 taps into 3 slots relative to a0 (footprint <= a0+2)
    float g0 = (1.0f - wy) * (1.0f - f0);
    float g1 = (1.0f - wy) * f0;
    float g2 = wy * (1.0f - f1);
    float g3 = wy * f1;
    float w0 = g0, w1 = 0.0f, w2 = 0.0f;
    if (a1 == a0) w0 += g1; else w1 += g1;
    if (b0 == a0) w0 += g2; else w1 += g2;
    int ob1 = b1 - a0;
    if (ob1 == 0) w0 += g3; else if (ob1 == 1) w1 += g3; else w2 += g3;
    float4 e;
    e.x = w0; e.y = w1; e.z = w2;
    e.w = __int_as_float(a0);        // patch-local base index [0,223]
    return e;
}

// kernel 1: entry tables + patch_indices tail
__global__ __launch_bounds__(448)
void entry_kernel(const int* __restrict__ tops,
                  const int* __restrict__ lefts,
                  const int* __restrict__ crop_hs,
                  const int* __restrict__ crop_ws,
                  float4* __restrict__ tab,
                  float* __restrict__ out, int out_size) {
    const int n = blockIdx.x;
    const int t = threadIdx.x;
    tab[n * IMG + t]        = make_entry(t, crop_ws[n], lefts[n]);  // colE
    tab[NTAB + n * IMG + t] = make_entry(t, crop_hs[n], tops[n]);   // rowE
    if (n == 0 && t < 128) {
        out[(size_t)out_size - 128 + t] = (float)(t & 3);
    }
}

// kernel 2: all-register separable resample
__global__ __launch_bounds__(448)
void roi_patch_kernel(const float* __restrict__ x,
                      const float4* __restrict__ tab,
                      float* __restrict__ out) {
    __shared__ float4 rowE[ROWS];

    const int n   = blockIdx.y;
    const int y0  = blockIdx.x * ROWS;
    const int tid = threadIdx.x;
    const int b   = n >> 2;
    const int gi  = (n >> 1) & 1;
    const int gj  = n & 1;

    // prologue: table loads replace ~90 VALU ops of make_entry
    const float4 ce = tab[n * IMG + tid];                  // col entry (b128)
    const float4 re0 = tab[NTAB + n * IMG + y0];           // uniform row entry
    if (tid < ROWS) rowE[tid] = tab[NTAB + n * IMG + y0 + tid];

    const int ca = __float_as_int(ce.w);
    const int cb = gj * PATCH;
    const int c0 = cb + ca;
    const int c1 = cb + min(ca + 1, 223);
    const int c2 = cb + min(ca + 2, 223);

    const int pr_min   = __float_as_int(re0.w);
    const int pr_min_s = __builtin_amdgcn_readfirstlane(pr_min);

    // padded row offsets: row k -> min(pr_min+k,223)
    int roff[NPR];
    #pragma unroll
    for (int k = 0; k < NPR; ++k)
        roff[k] = (min(pr_min + k, 223) - pr_min) * IMG;

    const float* xb = x + (size_t)b * 3 * IMG * IMG + (size_t)(gi * PATCH + pr_min) * IMG;
    float* ob = out + (size_t)n * 3 * IMG * IMG + (size_t)y0 * IMG + tid;

    float v0[NPR], v1[NPR], v2[NPR], h[NPR];

#define GATHER(CH)                                                        \
    {                                                                     \
        const float* xc = xb + (size_t)(CH) * IMG * IMG;                  \
        _Pragma("unroll")                                                 \
        for (int k = 0; k < NPR; ++k) {                                   \
            const float* xr = xc + roff[k];                               \
            v0[k] = xr[c0]; v1[k] = xr[c1]; v2[k] = xr[c2];               \
        }                                                                 \
    }

#define HFOLD()                                                           \
    {                                                                     \
        _Pragma("unroll")                                                 \
        for (int k = 0; k < NPR; ++k)                                     \
            h[k] = ce.x * v0[k] + ce.y * v1[k] + ce.z * v2[k];            \
    }

    // vertical pass: block-uniform k0 (<=4), scalarized switch -> static regs
#define VPASS(CH)                                                         \
    {                                                                     \
        float* orow = ob + (size_t)(CH) * IMG * IMG;                      \
        _Pragma("unroll")                                                 \
        for (int r = 0; r < ROWS; ++r) {                                  \
            const float4 re = rowE[r];                                    \
            const int k0 = __builtin_amdgcn_readfirstlane(                \
                               __float_as_int(re.w)) - pr_min_s;          \
            float v;                                                      \
            switch (k0) {                                                 \
            case 0:  v = re.x * h[0] + re.y * h[1] + re.z * h[2]; break;  \
            case 1:  v = re.x * h[1] + re.y * h[2] + re.z * h[3]; break;  \
            case 2:  v = re.x * h[2] + re.y * h[3] + re.z * h[4]; break;  \
            case 3:  v = re.x * h[3] + re.y * h[4] + re.z * h[5]; break;  \
            case 4:  v = re.x * h[4] + re.y * h[5] + re.z * h[6]; break;  \
            default: v = re.x * h[5] + re.y * h[6] + re.z * h[7]; break;  \
            }                                                             \
            *orow = v;                                                    \
            orow += IMG;                                                  \
        }                                                                 \
    }

    // channel 0 gathers in flight across the rowE barrier
    GATHER(0);
    SOFT_BARRIER();          // publishes rowE; does not drain gathers

    HFOLD();
    VPASS(0);

    GATHER(1);
    HFOLD();
    VPASS(1);

    GATHER(2);
    HFOLD();
    VPASS(2);

#undef GATHER
#undef HFOLD
#undef VPASS
}

extern "C" void kernel_launch(void* const* d_in, const int* in_sizes, int n_in,
                              void* d_out, int out_size, void* d_ws, size_t ws_size,
                              hipStream_t stream) {
    const float* x        = (const float*)d_in[0];
    const int*   tops     = (const int*)d_in[1];
    const int*   lefts    = (const int*)d_in[2];
    const int*   crop_hs  = (const int*)d_in[3];
    const int*   crop_ws  = (const int*)d_in[4];
    float*       out      = (float*)d_out;
    float4*      tab      = (float4*)d_ws;   // 2 x 128 x 448 x 16B = 1.83 MB

    entry_kernel<<<128, IMG, 0, stream>>>(tops, lefts, crop_hs, crop_ws,
                                          tab, out, out_size);

    dim3 grid(IMG / ROWS, 128);   // 56 x 128 blocks
    dim3 block(IMG);              // 448 threads = 7 waves
    roi_patch_kernel<<<grid, block, 0, stream>>>(x, tab, out);
}

// Round 12
// 116.778 us; speedup vs baseline: 1.0099x; 1.0099x over previous
//
#include <hip/hip_runtime.h>

// ROIPatchExtractor: B=32, C=3, H=W=448, 2x2 patches -> N=128 samples.
// Composed separable bilinear: each output row/col = weighted 3-tap sum of
// <=3 consecutive patch rows/cols.
//
// r12: MAX-OCCUPANCY all-register design. r2-r11 post-mortems refuted every
// issue-side theory (LDS pipe, barriers, gather/store instr count, vmcnt
// drain, prologue VALU) -- the kernel is latency-exposed. r1's profile
// showed Occupancy 54.7% despite a theoretical 87.5% for 448-thread blocks.
// Here: 256-thread blocks, __launch_bounds__(256,8) -> 8 blocks/CU =
// 32 waves/CU = 100% occupancy, VGPR<=64. Each wave independently owns
// 4 output rows x 64 cols x 3 channels: NPR=5 patch-row window (a0 span<=2
// over 4 rows + 3 taps), 15 gathers/ch into registers, hfold, vpass with
// per-wave-uniform window indices (SGPR switch). Row-entry weights are
// broadcast to SGPRs via readlane. Zero LDS, zero barriers.

#define IMG 448
#define PATCH 224
#define NPR 5      // padded patch-row window per wave (4 rows: span<=2, +3 taps)

__device__ inline float4 make_entry(int t, int crop, int off) {
    // stage 2: output coord t -> up-image coords u0,u1 with weight wy
    float cf = (float)crop;
    float s = ((float)t + 0.5f) * cf / 448.0f - 0.5f;
    s = fminf(fmaxf(s, 0.0f), cf - 1.0f);
    int i0 = (int)s;                 // s >= 0, trunc == floor
    int i1 = min(i0 + 1, crop - 1);
    float wy = s - (float)i0;
    int u0 = off + i0;
    int u1 = off + i1;
    // stage 1: up coord u -> patch coord: s1 = 0.5*u - 0.25, clamp [0,223]
    float t0 = fminf(fmaxf(0.5f * (float)u0 - 0.25f, 0.0f), 223.0f);
    int a0 = (int)t0;
    int a1 = min(a0 + 1, 223);
    float f0 = t0 - (float)a0;
    float t1 = fminf(fmaxf(0.5f * (float)u1 - 0.25f, 0.0f), 223.0f);
    int b0 = (int)t1;
    int b1 = min(b0 + 1, 223);
    float f1 = t1 - (float)b0;
    // fold 4 taps into 3 slots relative to a0 (footprint <= a0+2)
    float g0 = (1.0f - wy) * (1.0f - f0);
    float g1 = (1.0f - wy) * f0;
    float g2 = wy * (1.0f - f1);
    float g3 = wy * f1;
    float w0 = g0, w1 = 0.0f, w2 = 0.0f;
    if (a1 == a0) w0 += g1; else w1 += g1;
    if (b0 == a0) w0 += g2; else w1 += g2;
    int ob1 = b1 - a0;
    if (ob1 == 0) w0 += g3; else if (ob1 == 1) w1 += g3; else w2 += g3;
    float4 e;
    e.x = w0; e.y = w1; e.z = w2;
    e.w = __int_as_float(a0);        // patch-local base index [0,223]
    return e;
}

__global__ __launch_bounds__(256, 8)
void roi_patch_kernel(const float* __restrict__ x,
                      const int* __restrict__ tops,
                      const int* __restrict__ lefts,
                      const int* __restrict__ crop_hs,
                      const int* __restrict__ crop_ws,
                      float* __restrict__ out,
                      int out_size) {
    const int n    = blockIdx.z;
    const int ct   = blockIdx.x;          // col tile 0..6 (64 cols each)
    const int y0   = blockIdx.y * 16;     // 16-row tile; wave wv owns 4 rows
    const int tid  = threadIdx.x;
    const int lane = tid & 63;
    const int wv   = tid >> 6;            // 0..3
    const int b    = n >> 2;
    const int gi   = (n >> 1) & 1;
    const int gj   = n & 1;

    const int chp = crop_hs[n], cwp = crop_ws[n];
    const int tp  = tops[n],    lf  = lefts[n];

    const int col = ct * 64 + lane;
    const int yw  = y0 + wv * 4;          // this wave's first output row

    // per-lane column entry
    const float4 ce = make_entry(col, cwp, lf);
    const int ca = __float_as_int(ce.w);
    const int cb = gj * PATCH;
    const int c0 = cb + ca;
    const int c1 = cb + min(ca + 1, 223);
    const int c2 = cb + min(ca + 2, 223);

    // row entries for the wave's 4 rows: lane r (r = lane&3) computes row
    // yw+r; broadcast components to SGPRs via readlane (uniform lane idx).
    const float4 rw = make_entry(yw + (lane & 3), chp, tp);
    float rex[4], rey[4], rez[4];
    int ra[4];
    #pragma unroll
    for (int r = 0; r < 4; ++r) {
        rex[r] = __int_as_float(__builtin_amdgcn_readlane(__float_as_int(rw.x), r));
        rey[r] = __int_as_float(__builtin_amdgcn_readlane(__float_as_int(rw.y), r));
        rez[r] = __int_as_float(__builtin_amdgcn_readlane(__float_as_int(rw.z), r));
        ra[r]  = __builtin_amdgcn_readlane(__float_as_int(rw.w), r);
    }
    const int pr_min = ra[0];             // wave-uniform window start

    // patch_indices tail (float values; harness reads flat buffer as f32)
    if (blockIdx.x == 0 && blockIdx.y == 0 && n == 0 && tid < 128) {
        out[(size_t)out_size - 128 + tid] = (float)(tid & 3);
    }

    // padded row offsets: window row k -> patch row min(pr_min+k,223)
    int roff[NPR];
    #pragma unroll
    for (int k = 0; k < NPR; ++k)
        roff[k] = (min(pr_min + k, 223) - pr_min) * IMG;

    const float* xb = x + (size_t)b * 3 * IMG * IMG
                        + (size_t)(gi * PATCH + pr_min) * IMG;
    float* ob = out + (size_t)n * 3 * IMG * IMG + (size_t)yw * IMG + col;

    float v0[NPR], v1[NPR], v2[NPR], h[NPR];

#define GATHER(CH)                                                        \
    {                                                                     \
        const float* xc = xb + (size_t)(CH) * IMG * IMG;                  \
        _Pragma("unroll")                                                 \
        for (int k = 0; k < NPR; ++k) {                                   \
            const float* xr = xc + roff[k];                               \
            v0[k] = xr[c0]; v1[k] = xr[c1]; v2[k] = xr[c2];               \
        }                                                                 \
    }

#define HFOLD()                                                           \
    {                                                                     \
        _Pragma("unroll")                                                 \
        for (int k = 0; k < NPR; ++k)                                     \
            h[k] = ce.x * v0[k] + ce.y * v1[k] + ce.z * v2[k];            \
    }

    // vertical pass: k0 = ra[r]-pr_min is wave-uniform and in {0,1,2}
#define VPASS(CH)                                                         \
    {                                                                     \
        float* orow = ob + (size_t)(CH) * IMG * IMG;                      \
        _Pragma("unroll")                                                 \
        for (int r = 0; r < 4; ++r) {                                     \
            const int k0 = ra[r] - pr_min;                                \
            float v;                                                      \
            switch (k0) {                                                 \
            case 0:  v = rex[r] * h[0] + rey[r] * h[1] + rez[r] * h[2]; break; \
            case 1:  v = rex[r] * h[1] + rey[r] * h[2] + rez[r] * h[3]; break; \
            default: v = rex[r] * h[2] + rey[r] * h[3] + rez[r] * h[4]; break; \
            }                                                             \
            orow[(size_t)r * IMG] = v;                                    \
        }                                                                 \
    }

    GATHER(0); HFOLD(); VPASS(0);
    GATHER(1); HFOLD(); VPASS(1);
    GATHER(2); HFOLD(); VPASS(2);

#undef GATHER
#undef HFOLD
#undef VPASS
}

extern "C" void kernel_launch(void* const* d_in, const int* in_sizes, int n_in,
                              void* d_out, int out_size, void* d_ws, size_t ws_size,
                              hipStream_t stream) {
    const float* x        = (const float*)d_in[0];
    const int*   tops     = (const int*)d_in[1];
    const int*   lefts    = (const int*)d_in[2];
    const int*   crop_hs  = (const int*)d_in[3];
    const int*   crop_ws  = (const int*)d_in[4];
    float*       out      = (float*)d_out;

    dim3 grid(7, 28, 128);   // col-tiles x row-tiles(16) x samples
    dim3 block(256);         // 4 waves; 8 blocks/CU -> 32 waves (100%)
    roi_patch_kernel<<<grid, block, 0, stream>>>(x, tops, lefts, crop_hs, crop_ws,
                                                 out, out_size);
}

// Round 13
// 99.543 us; speedup vs baseline: 1.1847x; 1.1731x over previous
//
#include <hip/hip_runtime.h>

// ROIPatchExtractor: B=32, C=3, H=W=448, 2x2 patches -> N=128 samples.
// Composed separable bilinear: each output row/col = weighted 3-tap sum of
// <=3 consecutive patch rows/cols.
//
// r13: TCP-THROUGHPUT design. Post-mortems r1-r12 fit one model: the wall is
// per-CU vector-memory (TA/TCP) processing (~4cyc/instr + 64B/cyc data), not
// occupancy/LDS/barriers/VALU. Fix both sides:
//  - each thread owns 4 consecutive cols x 4 consecutive rows x 3 ch;
//  - gather = ONE dwordx4 + dword per window row (5-float window serves all
//    4 cols: 5B/px through TCP vs 12B/px, 2 instrs vs 12);
//  - per-col 3-tap weights repositioned into static 5-slot vectors W[j][s]
//    (select-accumulate, branchless, no dynamic indexing);
//  - store = dwordx4 (4x fewer store instrs, 1KB per wave-instr);
//  - vertical pass muxes a per-thread k0 in {0,1,2} via cndmask ladders.

#define IMG 448
#define PATCH 224
#define BROWS 16   // output rows per block
#define NPR 5      // per-thread patch-row window (4 rows: span<=2, +3 taps)
#define NQ 112

#define SOFT_BARRIER()                                          \
    do {                                                        \
        asm volatile("s_waitcnt lgkmcnt(0)" ::: "memory");      \
        __builtin_amdgcn_s_barrier();                           \
        asm volatile("" ::: "memory");                          \
    } while (0)

__device__ inline float4 make_entry(int t, int crop, int off) {
    // stage 2: output coord t -> up-image coords u0,u1 with weight wy
    float cf = (float)crop;
    float s = ((float)t + 0.5f) * cf / 448.0f - 0.5f;
    s = fminf(fmaxf(s, 0.0f), cf - 1.0f);
    int i0 = (int)s;
    int i1 = min(i0 + 1, crop - 1);
    float wy = s - (float)i0;
    int u0 = off + i0;
    int u1 = off + i1;
    // stage 1: up coord u -> patch coord: s1 = 0.5*u - 0.25, clamp [0,223]
    float t0 = fminf(fmaxf(0.5f * (float)u0 - 0.25f, 0.0f), 223.0f);
    int a0 = (int)t0;
    int a1 = min(a0 + 1, 223);
    float f0 = t0 - (float)a0;
    float t1 = fminf(fmaxf(0.5f * (float)u1 - 0.25f, 0.0f), 223.0f);
    int b0 = (int)t1;
    int b1 = min(b0 + 1, 223);
    float f1 = t1 - (float)b0;
    // fold 4 taps into 3 slots relative to a0 (footprint <= a0+2)
    float g0 = (1.0f - wy) * (1.0f - f0);
    float g1 = (1.0f - wy) * f0;
    float g2 = wy * (1.0f - f1);
    float g3 = wy * f1;
    float w0 = g0, w1 = 0.0f, w2 = 0.0f;
    if (a1 == a0) w0 += g1; else w1 += g1;
    if (b0 == a0) w0 += g2; else w1 += g2;
    int ob1 = b1 - a0;
    if (ob1 == 0) w0 += g3; else if (ob1 == 1) w1 += g3; else w2 += g3;
    float4 e;
    e.x = w0; e.y = w1; e.z = w2;
    e.w = __int_as_float(a0);        // patch-local base index [0,223]
    return e;
}

__global__ __launch_bounds__(448)
void roi_patch_kernel(const float* __restrict__ x,
                      const int* __restrict__ tops,
                      const int* __restrict__ lefts,
                      const int* __restrict__ crop_hs,
                      const int* __restrict__ crop_ws,
                      float* __restrict__ out,
                      int out_size) {
    __shared__ float4 colE[IMG];
    __shared__ float4 rowE[BROWS];

    const int n   = blockIdx.y;
    const int y0  = blockIdx.x * BROWS;
    const int tid = threadIdx.x;
    const int b   = n >> 2;
    const int gi  = (n >> 1) & 1;
    const int gj  = n & 1;

    const int chp = crop_hs[n], cwp = crop_ws[n];
    const int tp  = tops[n],    lf  = lefts[n];

    colE[tid] = make_entry(tid, cwp, lf);
    if (tid < BROWS) rowE[tid] = make_entry(y0 + tid, chp, tp);

    // patch_indices tail (float values; harness reads flat buffer as f32)
    if (blockIdx.x == 0 && n == 0 && tid < 128) {
        out[(size_t)out_size - 128 + tid] = (float)(tid & 3);
    }
    SOFT_BARRIER();

    const int q  = tid % NQ;   // col quad: cols 4q..4q+3
    const int rg = tid / NQ;   // row group: rows rg*4..rg*4+3 of the 16-row tile

    // ---- column side: 5-slot repositioned weights over window [base,base+4]
    int base;
    float W[4][NPR];
    {
        const float4 e0 = colE[4 * q];
        base = min(__float_as_int(e0.w), 219);   // window fits [0,223]
        #pragma unroll
        for (int j = 0; j < 4; ++j) {
            const float4 e = colE[4 * q + j];
            const int ca = __float_as_int(e.w);
            const int s0 = ca - base;                 // 0..4
            const int s1 = min(ca + 1, 223) - base;   // 0..4
            const int s2 = min(ca + 2, 223) - base;   // 0..4
            #pragma unroll
            for (int s = 0; s < NPR; ++s) {
                W[j][s] = (s0 == s ? e.x : 0.f)
                        + (s1 == s ? e.y : 0.f)
                        + (s2 == s ? e.z : 0.f);
            }
        }
    }

    // ---- row side: 4 rows, k0 in {0,1,2} relative to this thread's pr_min
    float rex[4], rey[4], rez[4];
    int k0[4];
    int pr_min;
    {
        const float4 r0 = rowE[rg * 4];
        pr_min = __float_as_int(r0.w);
        #pragma unroll
        for (int r = 0; r < 4; ++r) {
            const float4 re = rowE[rg * 4 + r];
            rex[r] = re.x; rey[r] = re.y; rez[r] = re.z;
            k0[r] = __float_as_int(re.w) - pr_min;    // 0..2
        }
    }

    int roff[NPR];
    #pragma unroll
    for (int k = 0; k < NPR; ++k)
        roff[k] = (min(pr_min + k, 223) - pr_min) * IMG;

    const float* xb = x + (size_t)b * 3 * IMG * IMG
                        + (size_t)(gi * PATCH + pr_min) * IMG
                        + (gj * PATCH + base);
    float* ob = out + (size_t)n * 3 * IMG * IMG
                    + (size_t)(y0 + rg * 4) * IMG + 4 * q;

    #pragma unroll 1
    for (int c = 0; c < 3; ++c) {
        const float* xc = xb + (size_t)c * IMG * IMG;

        // gathers: 5 window rows x (dwordx4 + dword) -- all independent
        float4 lo[NPR]; float hi[NPR];
        #pragma unroll
        for (int k = 0; k < NPR; ++k) {
            const float* p = xc + roff[k];
            lo[k] = *reinterpret_cast<const float4*>(p);  // 4B-aligned ok (r8)
            hi[k] = p[4];
        }

        // horizontal fold: h[k][j] = dot5(W[j], win[k])
        float h[NPR][4];
        #pragma unroll
        for (int k = 0; k < NPR; ++k) {
            #pragma unroll
            for (int j = 0; j < 4; ++j) {
                h[k][j] = W[j][0] * lo[k].x + W[j][1] * lo[k].y
                        + W[j][2] * lo[k].z + W[j][3] * lo[k].w
                        + W[j][4] * hi[k];
            }
        }

        // vertical pass: per-row 3-tap over h[k0..k0+2], k0 in {0,1,2}
        float* orow = ob + (size_t)c * IMG * IMG;
        #pragma unroll
        for (int r = 0; r < 4; ++r) {
            const bool e0 = (k0[r] == 0);
            const bool e1 = (k0[r] == 1);
            float4 v;
            #pragma unroll
            for (int j = 0; j < 4; ++j) {
                const float a = e0 ? h[0][j] : (e1 ? h[1][j] : h[2][j]);
                const float bb = e0 ? h[1][j] : (e1 ? h[2][j] : h[3][j]);
                const float cc = e0 ? h[2][j] : (e1 ? h[3][j] : h[4][j]);
                const float o = rex[r] * a + rey[r] * bb + rez[r] * cc;
                if (j == 0) v.x = o; else if (j == 1) v.y = o;
                else if (j == 2) v.z = o; else v.w = o;
            }
            *reinterpret_cast<float4*>(orow + (size_t)r * IMG) = v;  // 16B-aligned
        }
    }
}

extern "C" void kernel_launch(void* const* d_in, const int* in_sizes, int n_in,
                              void* d_out, int out_size, void* d_ws, size_t ws_size,
                              hipStream_t stream) {
    const float* x        = (const float*)d_in[0];
    const int*   tops     = (const int*)d_in[1];
    const int*   lefts    = (const int*)d_in[2];
    const int*   crop_hs  = (const int*)d_in[3];
    const int*   crop_ws  = (const int*)d_in[4];
    float*       out      = (float*)d_out;

    dim3 grid(IMG / BROWS, 128);   // 28 x 128 blocks
    dim3 block(448);               // 112 col-quads x 4 row-groups
    roi_patch_kernel<<<grid, block, 0, stream>>>(x, tops, lefts, crop_hs, crop_ws,
                                                 out, out_size);
}

// Round 14
// 63.614 us; speedup vs baseline: 1.8538x; 1.5648x over previous
//
#include <hip/hip_runtime.h>

// ROIPatchExtractor: B=32, C=3, H=W=448, 2x2 patches -> N=128 samples.
// Composed separable bilinear: each output row/col = weighted 3-tap sum of
// <=3 consecutive patch rows/cols.
//
// r14 = r13 (TCP design: 4col x 4row per thread, dwordx4+dword window
// gathers, dwordx4 stores) + three CU-work cuts, per the serial-sum model
// (total ~= CU-side work + HBM time; they don't overlap under write
// back-pressure):
//  1. repositioned ROW weights Rw[4][5] (prologue selects) -> vpass is a
//     dense 5-FMA dot, no cndmask ladders in the hot loop;
//  2. explicit next-channel dwordx4 prefetch before current vpass (gather
//     latency hides under compute, r7 mechanism in registers);
//  3. nontemporal stores: 301MB write stream stops evicting the 77MB input
//     from L2/L3.

typedef float f32x4 __attribute__((ext_vector_type(4)));

#define IMG 448
#define PATCH 224
#define BROWS 16   // output rows per block
#define NPR 5      // per-thread patch-row window (4 rows: span<=2, +3 taps)
#define NQ 112

#define SOFT_BARRIER()                                          \
    do {                                                        \
        asm volatile("s_waitcnt lgkmcnt(0)" ::: "memory");      \
        __builtin_amdgcn_s_barrier();                           \
        asm volatile("" ::: "memory");                          \
    } while (0)

__device__ inline float4 make_entry(int t, int crop, int off) {
    // stage 2: output coord t -> up-image coords u0,u1 with weight wy
    float cf = (float)crop;
    float s = ((float)t + 0.5f) * cf / 448.0f - 0.5f;
    s = fminf(fmaxf(s, 0.0f), cf - 1.0f);
    int i0 = (int)s;
    int i1 = min(i0 + 1, crop - 1);
    float wy = s - (float)i0;
    int u0 = off + i0;
    int u1 = off + i1;
    // stage 1: up coord u -> patch coord: s1 = 0.5*u - 0.25, clamp [0,223]
    float t0 = fminf(fmaxf(0.5f * (float)u0 - 0.25f, 0.0f), 223.0f);
    int a0 = (int)t0;
    int a1 = min(a0 + 1, 223);
    float f0 = t0 - (float)a0;
    float t1 = fminf(fmaxf(0.5f * (float)u1 - 0.25f, 0.0f), 223.0f);
    int b0 = (int)t1;
    int b1 = min(b0 + 1, 223);
    float f1 = t1 - (float)b0;
    // fold 4 taps into 3 slots relative to a0 (footprint <= a0+2)
    float g0 = (1.0f - wy) * (1.0f - f0);
    float g1 = (1.0f - wy) * f0;
    float g2 = wy * (1.0f - f1);
    float g3 = wy * f1;
    float w0 = g0, w1 = 0.0f, w2 = 0.0f;
    if (a1 == a0) w0 += g1; else w1 += g1;
    if (b0 == a0) w0 += g2; else w1 += g2;
    int ob1 = b1 - a0;
    if (ob1 == 0) w0 += g3; else if (ob1 == 1) w1 += g3; else w2 += g3;
    float4 e;
    e.x = w0; e.y = w1; e.z = w2;
    e.w = __int_as_float(a0);        // patch-local base index [0,223]
    return e;
}

__global__ __launch_bounds__(448)
void roi_patch_kernel(const float* __restrict__ x,
                      const int* __restrict__ tops,
                      const int* __restrict__ lefts,
                      const int* __restrict__ crop_hs,
                      const int* __restrict__ crop_ws,
                      float* __restrict__ out,
                      int out_size) {
    __shared__ float4 colE[IMG];
    __shared__ float4 rowE[BROWS];

    const int n   = blockIdx.y;
    const int y0  = blockIdx.x * BROWS;
    const int tid = threadIdx.x;
    const int b   = n >> 2;
    const int gi  = (n >> 1) & 1;
    const int gj  = n & 1;

    const int chp = crop_hs[n], cwp = crop_ws[n];
    const int tp  = tops[n],    lf  = lefts[n];

    colE[tid] = make_entry(tid, cwp, lf);
    if (tid < BROWS) rowE[tid] = make_entry(y0 + tid, chp, tp);

    // patch_indices tail (float values; harness reads flat buffer as f32)
    if (blockIdx.x == 0 && n == 0 && tid < 128) {
        out[(size_t)out_size - 128 + tid] = (float)(tid & 3);
    }
    SOFT_BARRIER();

    const int q  = tid % NQ;   // col quad: cols 4q..4q+3
    const int rg = tid / NQ;   // row group: rows rg*4..rg*4+3 of the 16-row tile

    // ---- column side: 5-slot repositioned weights over window [base,base+4]
    int base;
    float W[4][NPR];
    {
        const float4 e0 = colE[4 * q];
        base = min(__float_as_int(e0.w), 219);   // window fits [0,223]
        #pragma unroll
        for (int j = 0; j < 4; ++j) {
            const float4 e = colE[4 * q + j];
            const int ca = __float_as_int(e.w);
            const int s0 = ca - base;                 // 0..4
            const int s1 = min(ca + 1, 223) - base;   // 0..4
            const int s2 = min(ca + 2, 223) - base;   // 0..4
            #pragma unroll
            for (int s = 0; s < NPR; ++s) {
                W[j][s] = (s0 == s ? e.x : 0.f)
                        + (s1 == s ? e.y : 0.f)
                        + (s2 == s ? e.z : 0.f);
            }
        }
    }

    // ---- row side: repositioned 5-slot row weights (k0 in {0,1,2})
    float Rw[4][NPR];
    int pr_min;
    {
        const float4 r0 = rowE[rg * 4];
        pr_min = __float_as_int(r0.w);
        #pragma unroll
        for (int r = 0; r < 4; ++r) {
            const float4 re = rowE[rg * 4 + r];
            const int k0 = __float_as_int(re.w) - pr_min;    // 0..2
            const bool e0 = (k0 == 0), e1 = (k0 == 1);
            Rw[r][0] = e0 ? re.x : 0.f;
            Rw[r][1] = e0 ? re.y : (e1 ? re.x : 0.f);
            Rw[r][2] = e0 ? re.z : (e1 ? re.y : re.x);
            Rw[r][3] = e1 ? re.z : (e0 ? 0.f : re.y);
            Rw[r][4] = (e0 || e1) ? 0.f : re.z;
        }
    }

    int roff[NPR];
    #pragma unroll
    for (int k = 0; k < NPR; ++k)
        roff[k] = (min(pr_min + k, 223) - pr_min) * IMG;

    const float* xb = x + (size_t)b * 3 * IMG * IMG
                        + (size_t)(gi * PATCH + pr_min) * IMG
                        + (gj * PATCH + base);
    float* ob = out + (size_t)n * 3 * IMG * IMG
                    + (size_t)(y0 + rg * 4) * IMG + 4 * q;

    f32x4 loA[NPR], loB[NPR];
    float hiA[NPR], hiB[NPR];
    float h[NPR][4];

#define LOADX4(LO, CH)                                                    \
    {                                                                     \
        const float* xc = xb + (size_t)(CH) * IMG * IMG;                  \
        _Pragma("unroll")                                                 \
        for (int k = 0; k < NPR; ++k)                                     \
            LO[k] = *reinterpret_cast<const f32x4*>(xc + roff[k]);        \
    }

#define LOADHI(HI, CH)                                                    \
    {                                                                     \
        const float* xc = xb + (size_t)(CH) * IMG * IMG;                  \
        _Pragma("unroll")                                                 \
        for (int k = 0; k < NPR; ++k)                                     \
            HI[k] = xc[roff[k] + 4];                                      \
    }

#define HFOLD(LO, HI)                                                     \
    {                                                                     \
        _Pragma("unroll")                                                 \
        for (int k = 0; k < NPR; ++k) {                                   \
            _Pragma("unroll")                                             \
            for (int j = 0; j < 4; ++j) {                                 \
                h[k][j] = W[j][0] * LO[k].x + W[j][1] * LO[k].y           \
                        + W[j][2] * LO[k].z + W[j][3] * LO[k].w           \
                        + W[j][4] * HI[k];                                \
            }                                                             \
        }                                                                 \
    }

#define VPASS(CH)                                                         \
    {                                                                     \
        float* orow = ob + (size_t)(CH) * IMG * IMG;                      \
        _Pragma("unroll")                                                 \
        for (int r = 0; r < 4; ++r) {                                     \
            f32x4 v;                                                      \
            _Pragma("unroll")                                             \
            for (int j = 0; j < 4; ++j) {                                 \
                v[j] = Rw[r][0] * h[0][j] + Rw[r][1] * h[1][j]            \
                     + Rw[r][2] * h[2][j] + Rw[r][3] * h[3][j]            \
                     + Rw[r][4] * h[4][j];                                \
            }                                                             \
            __builtin_nontemporal_store(                                  \
                v, reinterpret_cast<f32x4*>(orow + (size_t)r * IMG));     \
        }                                                                 \
    }

    // channel-pipelined: issue next channel's wide loads before current vpass
    LOADX4(loA, 0); LOADHI(hiA, 0);
    LOADX4(loB, 1);                 // ch1 x4 loads in flight
    HFOLD(loA, hiA);                // h = ch0
    LOADHI(hiB, 1);
    VPASS(0);
    LOADX4(loA, 2);                 // ch2 x4 loads in flight
    HFOLD(loB, hiB);                // h = ch1
    LOADHI(hiA, 2);
    VPASS(1);
    HFOLD(loA, hiA);                // h = ch2
    VPASS(2);

#undef LOADX4
#undef LOADHI
#undef HFOLD
#undef VPASS
}

extern "C" void kernel_launch(void* const* d_in, const int* in_sizes, int n_in,
                              void* d_out, int out_size, void* d_ws, size_t ws_size,
                              hipStream_t stream) {
    const float* x        = (const float*)d_in[0];
    const int*   tops     = (const int*)d_in[1];
    const int*   lefts    = (const int*)d_in[2];
    const int*   crop_hs  = (const int*)d_in[3];
    const int*   crop_ws  = (const int*)d_in[4];
    float*       out      = (float*)d_out;

    dim3 grid(IMG / BROWS, 128);   // 28 x 128 blocks
    dim3 block(448);               // 112 col-quads x 4 row-groups
    roi_patch_kernel<<<grid, block, 0, stream>>>(x, tops, lefts, crop_hs, crop_ws,
                                                 out, out_size);
}

// Round 15
// 63.592 us; speedup vs baseline: 1.8545x; 1.0004x over previous
//
#include <hip/hip_runtime.h>

// ROIPatchExtractor: B=32, C=3, H=W=448, 2x2 patches -> N=128 samples.
// Composed separable bilinear: each output row/col = weighted 3-tap sum of
// <=3 consecutive patch rows/cols.
//
// r15 = r14 (TCP design + repositioned row weights + channel prefetch +
// nontemporal stores) + __launch_bounds__(448, 2).
// Post-mortem r14: estimated live state ~130 VGPR -- just past the 128
// occupancy cliff (m69: waves/SIMD halve at 64/128/256), i.e. ONE resident
// 7-wave block per CU. Capping at 128 VGPR doubles residency to 2 blocks/CU
// (14 waves), thickening latency hiding over the ~50us HBM floor.
// Single-variable experiment vs r14.

typedef float f32x4 __attribute__((ext_vector_type(4)));

#define IMG 448
#define PATCH 224
#define BROWS 16   // output rows per block
#define NPR 5      // per-thread patch-row window (4 rows: span<=2, +3 taps)
#define NQ 112

#define SOFT_BARRIER()                                          \
    do {                                                        \
        asm volatile("s_waitcnt lgkmcnt(0)" ::: "memory");      \
        __builtin_amdgcn_s_barrier();                           \
        asm volatile("" ::: "memory");                          \
    } while (0)

__device__ inline float4 make_entry(int t, int crop, int off) {
    // stage 2: output coord t -> up-image coords u0,u1 with weight wy
    float cf = (float)crop;
    float s = ((float)t + 0.5f) * cf / 448.0f - 0.5f;
    s = fminf(fmaxf(s, 0.0f), cf - 1.0f);
    int i0 = (int)s;
    int i1 = min(i0 + 1, crop - 1);
    float wy = s - (float)i0;
    int u0 = off + i0;
    int u1 = off + i1;
    // stage 1: up coord u -> patch coord: s1 = 0.5*u - 0.25, clamp [0,223]
    float t0 = fminf(fmaxf(0.5f * (float)u0 - 0.25f, 0.0f), 223.0f);
    int a0 = (int)t0;
    int a1 = min(a0 + 1, 223);
    float f0 = t0 - (float)a0;
    float t1 = fminf(fmaxf(0.5f * (float)u1 - 0.25f, 0.0f), 223.0f);
    int b0 = (int)t1;
    int b1 = min(b0 + 1, 223);
    float f1 = t1 - (float)b0;
    // fold 4 taps into 3 slots relative to a0 (footprint <= a0+2)
    float g0 = (1.0f - wy) * (1.0f - f0);
    float g1 = (1.0f - wy) * f0;
    float g2 = wy * (1.0f - f1);
    float g3 = wy * f1;
    float w0 = g0, w1 = 0.0f, w2 = 0.0f;
    if (a1 == a0) w0 += g1; else w1 += g1;
    if (b0 == a0) w0 += g2; else w1 += g2;
    int ob1 = b1 - a0;
    if (ob1 == 0) w0 += g3; else if (ob1 == 1) w1 += g3; else w2 += g3;
    float4 e;
    e.x = w0; e.y = w1; e.z = w2;
    e.w = __int_as_float(a0);        // patch-local base index [0,223]
    return e;
}

__global__ __launch_bounds__(448, 2)
void roi_patch_kernel(const float* __restrict__ x,
                      const int* __restrict__ tops,
                      const int* __restrict__ lefts,
                      const int* __restrict__ crop_hs,
                      const int* __restrict__ crop_ws,
                      float* __restrict__ out,
                      int out_size) {
    __shared__ float4 colE[IMG];
    __shared__ float4 rowE[BROWS];

    const int n   = blockIdx.y;
    const int y0  = blockIdx.x * BROWS;
    const int tid = threadIdx.x;
    const int b   = n >> 2;
    const int gi  = (n >> 1) & 1;
    const int gj  = n & 1;

    const int chp = crop_hs[n], cwp = crop_ws[n];
    const int tp  = tops[n],    lf  = lefts[n];

    colE[tid] = make_entry(tid, cwp, lf);
    if (tid < BROWS) rowE[tid] = make_entry(y0 + tid, chp, tp);

    // patch_indices tail (float values; harness reads flat buffer as f32)
    if (blockIdx.x == 0 && n == 0 && tid < 128) {
        out[(size_t)out_size - 128 + tid] = (float)(tid & 3);
    }
    SOFT_BARRIER();

    const int q  = tid % NQ;   // col quad: cols 4q..4q+3
    const int rg = tid / NQ;   // row group: rows rg*4..rg*4+3 of the 16-row tile

    // ---- column side: 5-slot repositioned weights over window [base,base+4]
    int base;
    float W[4][NPR];
    {
        const float4 e0 = colE[4 * q];
        base = min(__float_as_int(e0.w), 219);   // window fits [0,223]
        #pragma unroll
        for (int j = 0; j < 4; ++j) {
            const float4 e = colE[4 * q + j];
            const int ca = __float_as_int(e.w);
            const int s0 = ca - base;                 // 0..4
            const int s1 = min(ca + 1, 223) - base;   // 0..4
            const int s2 = min(ca + 2, 223) - base;   // 0..4
            #pragma unroll
            for (int s = 0; s < NPR; ++s) {
                W[j][s] = (s0 == s ? e.x : 0.f)
                        + (s1 == s ? e.y : 0.f)
                        + (s2 == s ? e.z : 0.f);
            }
        }
    }

    // ---- row side: repositioned 5-slot row weights (k0 in {0,1,2})
    float Rw[4][NPR];
    int pr_min;
    {
        const float4 r0 = rowE[rg * 4];
        pr_min = __float_as_int(r0.w);
        #pragma unroll
        for (int r = 0; r < 4; ++r) {
            const float4 re = rowE[rg * 4 + r];
            const int k0 = __float_as_int(re.w) - pr_min;    // 0..2
            const bool e0 = (k0 == 0), e1 = (k0 == 1);
            Rw[r][0] = e0 ? re.x : 0.f;
            Rw[r][1] = e0 ? re.y : (e1 ? re.x : 0.f);
            Rw[r][2] = e0 ? re.z : (e1 ? re.y : re.x);
            Rw[r][3] = e1 ? re.z : (e0 ? 0.f : re.y);
            Rw[r][4] = (e0 || e1) ? 0.f : re.z;
        }
    }

    int roff[NPR];
    #pragma unroll
    for (int k = 0; k < NPR; ++k)
        roff[k] = (min(pr_min + k, 223) - pr_min) * IMG;

    const float* xb = x + (size_t)b * 3 * IMG * IMG
                        + (size_t)(gi * PATCH + pr_min) * IMG
                        + (gj * PATCH + base);
    float* ob = out + (size_t)n * 3 * IMG * IMG
                    + (size_t)(y0 + rg * 4) * IMG + 4 * q;

    f32x4 loA[NPR], loB[NPR];
    float hiA[NPR], hiB[NPR];
    float h[NPR][4];

#define LOADX4(LO, CH)                                                    \
    {                                                                     \
        const float* xc = xb + (size_t)(CH) * IMG * IMG;                  \
        _Pragma("unroll")                                                 \
        for (int k = 0; k < NPR; ++k)                                     \
            LO[k] = *reinterpret_cast<const f32x4*>(xc + roff[k]);        \
    }

#define LOADHI(HI, CH)                                                    \
    {                                                                     \
        const float* xc = xb + (size_t)(CH) * IMG * IMG;                  \
        _Pragma("unroll")                                                 \
        for (int k = 0; k < NPR; ++k)                                     \
            HI[k] = xc[roff[k] + 4];                                      \
    }

#define HFOLD(LO, HI)                                                     \
    {                                                                     \
        _Pragma("unroll")                                                 \
        for (int k = 0; k < NPR; ++k) {                                   \
            _Pragma("unroll")                                             \
            for (int j = 0; j < 4; ++j) {                                 \
                h[k][j] = W[j][0] * LO[k].x + W[j][1] * LO[k].y           \
                        + W[j][2] * LO[k].z + W[j][3] * LO[k].w           \
                        + W[j][4] * HI[k];                                \
            }                                                             \
        }                                                                 \
    }

#define VPASS(CH)                                                         \
    {                                                                     \
        float* orow = ob + (size_t)(CH) * IMG * IMG;                      \
        _Pragma("unroll")                                                 \
        for (int r = 0; r < 4; ++r) {                                     \
            f32x4 v;                                                      \
            _Pragma("unroll")                                             \
            for (int j = 0; j < 4; ++j) {                                 \
                v[j] = Rw[r][0] * h[0][j] + Rw[r][1] * h[1][j]            \
                     + Rw[r][2] * h[2][j] + Rw[r][3] * h[3][j]            \
                     + Rw[r][4] * h[4][j];                                \
            }                                                             \
            __builtin_nontemporal_store(                                  \
                v, reinterpret_cast<f32x4*>(orow + (size_t)r * IMG));     \
        }                                                                 \
    }

    // channel-pipelined: issue next channel's wide loads before current vpass
    LOADX4(loA, 0); LOADHI(hiA, 0);
    LOADX4(loB, 1);                 // ch1 x4 loads in flight
    HFOLD(loA, hiA);                // h = ch0
    LOADHI(hiB, 1);
    VPASS(0);
    LOADX4(loA, 2);                 // ch2 x4 loads in flight
    HFOLD(loB, hiB);                // h = ch1
    LOADHI(hiA, 2);
    VPASS(1);
    HFOLD(loA, hiA);                // h = ch2
    VPASS(2);

#undef LOADX4
#undef LOADHI
#undef HFOLD
#undef VPASS
}

extern "C" void kernel_launch(void* const* d_in, const int* in_sizes, int n_in,
                              void* d_out, int out_size, void* d_ws, size_t ws_size,
                              hipStream_t stream) {
    const float* x        = (const float*)d_in[0];
    const int*   tops     = (const int*)d_in[1];
    const int*   lefts    = (const int*)d_in[2];
    const int*   crop_hs  = (const int*)d_in[3];
    const int*   crop_ws  = (const int*)d_in[4];
    float*       out      = (float*)d_out;

    dim3 grid(IMG / BROWS, 128);   // 28 x 128 blocks
    dim3 block(448);               // 112 col-quads x 4 row-groups
    roi_patch_kernel<<<grid, block, 0, stream>>>(x, tops, lefts, crop_hs, crop_ws,
                                                 out, out_size);
}

// Round 16
// 63.565 us; speedup vs baseline: 1.8553x; 1.0004x over previous
//
#include <hip/hip_runtime.h>

// ROIPatchExtractor: B=32, C=3, H=W=448, 2x2 patches -> N=128 samples.
// Composed separable bilinear: each output row/col = weighted 3-tap sum of
// <=3 consecutive patch rows/cols.
//
// r16 = r14/r15 (TCP design + repositioned weights + channel prefetch +
// nontemporal stores) with the dense dots PACKED into float2 j-pairs so the
// backend emits v_pk_fma_f32 (gfx950 packed-FP32, 2 FLOP-pairs/instr):
// HFOLD+VPASS instruction count halves (540 -> ~270 per thread), cutting
// the ~44us/CU VALU term to ~25us; HBM mixed-stream (~55us) becomes the
// sole wall if the model is right.

typedef float f32x4 __attribute__((ext_vector_type(4)));
typedef float f32x2 __attribute__((ext_vector_type(2)));

#define IMG 448
#define PATCH 224
#define BROWS 16   // output rows per block
#define NPR 5      // per-thread patch-row window (4 rows: span<=2, +3 taps)
#define NQ 112

#define SOFT_BARRIER()                                          \
    do {                                                        \
        asm volatile("s_waitcnt lgkmcnt(0)" ::: "memory");      \
        __builtin_amdgcn_s_barrier();                           \
        asm volatile("" ::: "memory");                          \
    } while (0)

__device__ inline float4 make_entry(int t, int crop, int off) {
    // stage 2: output coord t -> up-image coords u0,u1 with weight wy
    float cf = (float)crop;
    float s = ((float)t + 0.5f) * cf / 448.0f - 0.5f;
    s = fminf(fmaxf(s, 0.0f), cf - 1.0f);
    int i0 = (int)s;
    int i1 = min(i0 + 1, crop - 1);
    float wy = s - (float)i0;
    int u0 = off + i0;
    int u1 = off + i1;
    // stage 1: up coord u -> patch coord: s1 = 0.5*u - 0.25, clamp [0,223]
    float t0 = fminf(fmaxf(0.5f * (float)u0 - 0.25f, 0.0f), 223.0f);
    int a0 = (int)t0;
    int a1 = min(a0 + 1, 223);
    float f0 = t0 - (float)a0;
    float t1 = fminf(fmaxf(0.5f * (float)u1 - 0.25f, 0.0f), 223.0f);
    int b0 = (int)t1;
    int b1 = min(b0 + 1, 223);
    float f1 = t1 - (float)b0;
    // fold 4 taps into 3 slots relative to a0 (footprint <= a0+2)
    float g0 = (1.0f - wy) * (1.0f - f0);
    float g1 = (1.0f - wy) * f0;
    float g2 = wy * (1.0f - f1);
    float g3 = wy * f1;
    float w0 = g0, w1 = 0.0f, w2 = 0.0f;
    if (a1 == a0) w0 += g1; else w1 += g1;
    if (b0 == a0) w0 += g2; else w1 += g2;
    int ob1 = b1 - a0;
    if (ob1 == 0) w0 += g3; else if (ob1 == 1) w1 += g3; else w2 += g3;
    float4 e;
    e.x = w0; e.y = w1; e.z = w2;
    e.w = __int_as_float(a0);        // patch-local base index [0,223]
    return e;
}

__global__ __launch_bounds__(448, 2)
void roi_patch_kernel(const float* __restrict__ x,
                      const int* __restrict__ tops,
                      const int* __restrict__ lefts,
                      const int* __restrict__ crop_hs,
                      const int* __restrict__ crop_ws,
                      float* __restrict__ out,
                      int out_size) {
    __shared__ float4 colE[IMG];
    __shared__ float4 rowE[BROWS];

    const int n   = blockIdx.y;
    const int y0  = blockIdx.x * BROWS;
    const int tid = threadIdx.x;
    const int b   = n >> 2;
    const int gi  = (n >> 1) & 1;
    const int gj  = n & 1;

    const int chp = crop_hs[n], cwp = crop_ws[n];
    const int tp  = tops[n],    lf  = lefts[n];

    colE[tid] = make_entry(tid, cwp, lf);
    if (tid < BROWS) rowE[tid] = make_entry(y0 + tid, chp, tp);

    // patch_indices tail (float values; harness reads flat buffer as f32)
    if (blockIdx.x == 0 && n == 0 && tid < 128) {
        out[(size_t)out_size - 128 + tid] = (float)(tid & 3);
    }
    SOFT_BARRIER();

    const int q  = tid % NQ;   // col quad: cols 4q..4q+3
    const int rg = tid / NQ;   // row group: rows rg*4..rg*4+3 of the 16-row tile

    // ---- column side: repositioned 5-slot weights, packed as j-pairs:
    //      W2[jp][s] = { W[2jp][s], W[2jp+1][s] }
    int base;
    f32x2 W2[2][NPR];
    {
        const float4 e0 = colE[4 * q];
        base = min(__float_as_int(e0.w), 219);   // window fits [0,223]
        #pragma unroll
        for (int jp = 0; jp < 2; ++jp) {
            #pragma unroll
            for (int half = 0; half < 2; ++half) {
                const int j = 2 * jp + half;
                const float4 e = colE[4 * q + j];
                const int ca = __float_as_int(e.w);
                const int s0 = ca - base;                 // 0..4
                const int s1 = min(ca + 1, 223) - base;   // 0..4
                const int s2 = min(ca + 2, 223) - base;   // 0..4
                #pragma unroll
                for (int s = 0; s < NPR; ++s) {
                    const float w = (s0 == s ? e.x : 0.f)
                                  + (s1 == s ? e.y : 0.f)
                                  + (s2 == s ? e.z : 0.f);
                    W2[jp][s][half] = w;
                }
            }
        }
    }

    // ---- row side: repositioned 5-slot row weights (k0 in {0,1,2})
    float Rw[4][NPR];
    int pr_min;
    {
        const float4 r0 = rowE[rg * 4];
        pr_min = __float_as_int(r0.w);
        #pragma unroll
        for (int r = 0; r < 4; ++r) {
            const float4 re = rowE[rg * 4 + r];
            const int k0 = __float_as_int(re.w) - pr_min;    // 0..2
            const bool e0 = (k0 == 0), e1 = (k0 == 1);
            Rw[r][0] = e0 ? re.x : 0.f;
            Rw[r][1] = e0 ? re.y : (e1 ? re.x : 0.f);
            Rw[r][2] = e0 ? re.z : (e1 ? re.y : re.x);
            Rw[r][3] = e1 ? re.z : (e0 ? 0.f : re.y);
            Rw[r][4] = (e0 || e1) ? 0.f : re.z;
        }
    }

    int roff[NPR];
    #pragma unroll
    for (int k = 0; k < NPR; ++k)
        roff[k] = (min(pr_min + k, 223) - pr_min) * IMG;

    const float* xb = x + (size_t)b * 3 * IMG * IMG
                        + (size_t)(gi * PATCH + pr_min) * IMG
                        + (gj * PATCH + base);
    float* ob = out + (size_t)n * 3 * IMG * IMG
                    + (size_t)(y0 + rg * 4) * IMG + 4 * q;

    f32x4 loA[NPR], loB[NPR];
    float hiA[NPR], hiB[NPR];
    f32x2 h2[NPR][2];   // packed j-pairs

#define LOADX4(LO, CH)                                                    \
    {                                                                     \
        const float* xc = xb + (size_t)(CH) * IMG * IMG;                  \
        _Pragma("unroll")                                                 \
        for (int k = 0; k < NPR; ++k)                                     \
            LO[k] = *reinterpret_cast<const f32x4*>(xc + roff[k]);        \
    }

#define LOADHI(HI, CH)                                                    \
    {                                                                     \
        const float* xc = xb + (size_t)(CH) * IMG * IMG;                  \
        _Pragma("unroll")                                                 \
        for (int k = 0; k < NPR; ++k)                                     \
            HI[k] = xc[roff[k] + 4];                                      \
    }

    // packed horizontal fold: scalar window value x f32x2 weight pair
#define HFOLD(LO, HI)                                                     \
    {                                                                     \
        _Pragma("unroll")                                                 \
        for (int k = 0; k < NPR; ++k) {                                   \
            _Pragma("unroll")                                             \
            for (int jp = 0; jp < 2; ++jp) {                              \
                h2[k][jp] = W2[jp][0] * LO[k].x + W2[jp][1] * LO[k].y     \
                          + W2[jp][2] * LO[k].z + W2[jp][3] * LO[k].w     \
                          + W2[jp][4] * HI[k];                            \
            }                                                             \
        }                                                                 \
    }

    // packed vertical pass: scalar row weight x f32x2 h pair
#define VPASS(CH)                                                         \
    {                                                                     \
        float* orow = ob + (size_t)(CH) * IMG * IMG;                      \
        _Pragma("unroll")                                                 \
        for (int r = 0; r < 4; ++r) {                                     \
            f32x2 v01 = Rw[r][0] * h2[0][0] + Rw[r][1] * h2[1][0]         \
                      + Rw[r][2] * h2[2][0] + Rw[r][3] * h2[3][0]         \
                      + Rw[r][4] * h2[4][0];                              \
            f32x2 v23 = Rw[r][0] * h2[0][1] + Rw[r][1] * h2[1][1]         \
                      + Rw[r][2] * h2[2][1] + Rw[r][3] * h2[3][1]         \
                      + Rw[r][4] * h2[4][1];                              \
            f32x4 v;                                                      \
            v.x = v01.x; v.y = v01.y; v.z = v23.x; v.w = v23.y;           \
            __builtin_nontemporal_store(                                  \
                v, reinterpret_cast<f32x4*>(orow + (size_t)r * IMG));     \
        }                                                                 \
    }

    // channel-pipelined: issue next channel's wide loads before current vpass
    LOADX4(loA, 0); LOADHI(hiA, 0);
    LOADX4(loB, 1);                 // ch1 x4 loads in flight
    HFOLD(loA, hiA);                // h = ch0
    LOADHI(hiB, 1);
    VPASS(0);
    LOADX4(loA, 2);                 // ch2 x4 loads in flight
    HFOLD(loB, hiB);                // h = ch1
    LOADHI(hiA, 2);
    VPASS(1);
    HFOLD(loA, hiA);                // h = ch2
    VPASS(2);

#undef LOADX4
#undef LOADHI
#undef HFOLD
#undef VPASS
}

extern "C" void kernel_launch(void* const* d_in, const int* in_sizes, int n_in,
                              void* d_out, int out_size, void* d_ws, size_t ws_size,
                              hipStream_t stream) {
    const float* x        = (const float*)d_in[0];
    const int*   tops     = (const int*)d_in[1];
    const int*   lefts    = (const int*)d_in[2];
    const int*   crop_hs  = (const int*)d_in[3];
    const int*   crop_ws  = (const int*)d_in[4];
    float*       out      = (float*)d_out;

    dim3 grid(IMG / BROWS, 128);   // 28 x 128 blocks
    dim3 block(448);               // 112 col-quads x 4 row-groups
    roi_patch_kernel<<<grid, block, 0, stream>>>(x, tops, lefts, crop_hs, crop_ws,
                                                 out, out_size);
}